// Round 15
// baseline (224.099 us; speedup 1.0000x reference)
//
#include <hip/hip_runtime.h>
#include <stdint.h>

#define Bd 2
#define Td 2048
#define Cd 1024
#define Hd 16
#define HDd 64
#define BT 4096

typedef _Float16 f16;
typedef __attribute__((ext_vector_type(8))) _Float16 f16x8;
typedef __attribute__((ext_vector_type(4))) _Float16 f16x4;
typedef __attribute__((ext_vector_type(2))) _Float16 f16x2;
typedef __attribute__((ext_vector_type(4))) float f32x4;
typedef __attribute__((ext_vector_type(16))) float f32x16;
typedef __attribute__((ext_vector_type(2))) unsigned uint2v;

#define GLD_LDS16(gptr, lptr)                                                        \
    __builtin_amdgcn_global_load_lds((const __attribute__((address_space(1))) void*)(gptr), \
                                     (__attribute__((address_space(3))) void*)(lptr), 16, 0, 0)

#define MAX3(a, b, c) fmaxf(fmaxf(a, b), c)
// raw v_exp_f32: exp2f() without -ffast-math lowers to a ~6-op denorm-guarded libcall;
// softmax inputs are <= 8 and underflow-to-0 is harmless (row max term is always 2^0).
#define EXP2(x) __builtin_amdgcn_exp2f(x)

// cross-half (lane i <-> lane i^32) value pair via permlane32_swap intrinsic (SSA-safe).
__device__ __forceinline__ float2 xhalf_pair(float v) {
    uint2v r = __builtin_amdgcn_permlane32_swap(__float_as_uint(v), __float_as_uint(v), false, false);
    unsigned lo = r[0], hi = r[1];
    float2 out;
    out.x = __uint_as_float(lo);
    out.y = __uint_as_float(hi);
    return out;
}

// ---------------- f32 -> f16 conversion (q,k,v,Wq,Wk,Wv,Wo) + fused trig table ----------------
__global__ void k_cvt(const float* __restrict__ q, const float* __restrict__ k,
                      const float* __restrict__ v, const float* __restrict__ wq,
                      const float* __restrict__ wk, const float* __restrict__ wv,
                      const float* __restrict__ wo, f16* __restrict__ qh, f16* __restrict__ kh,
                      f16* __restrict__ vh, f16* __restrict__ wqh, f16* __restrict__ wkh,
                      f16* __restrict__ wvh, f16* __restrict__ woh,
                      const float* __restrict__ freqs, float2* __restrict__ csT) {
    int g = blockIdx.x * 256 + threadIdx.x;
    if (g >= 4194304) {  // trig tail: 65536 elems
        int i = g - 4194304;
        float f = freqs[i];
        float2 cs;
        cs.x = cosf(f);
        cs.y = sinf(f);
        csT[i] = cs;
        return;
    }
    const float* src;
    f16* dst;
    int base;
    if (g < 1048576)      { src = q;  dst = qh;  base = 0; }
    else if (g < 2097152) { src = k;  dst = kh;  base = 1048576; }
    else if (g < 3145728) { src = v;  dst = vh;  base = 2097152; }
    else if (g < 3407872) { src = wq; dst = wqh; base = 3145728; }
    else if (g < 3670016) { src = wk; dst = wkh; base = 3407872; }
    else if (g < 3932160) { src = wv; dst = wvh; base = 3670016; }
    else                  { src = wo; dst = woh; base = 3932160; }
    int i = g - base;
    float4 val = reinterpret_cast<const float4*>(src)[i];
    f16x4 o;
    o[0] = (f16)val.x; o[1] = (f16)val.y; o[2] = (f16)val.z; o[3] = (f16)val.w;
    reinterpret_cast<f16x4*>(dst)[i] = o;
}

// ---------------- shared GEMM main loop (BK=64, both-sides XOR swizzle, 128x128 tile) ----------
#define GEMM_MAINLOOP(A, W)                                                                  \
    const int tid = threadIdx.x;                                                             \
    const int lane = tid & 63, w = tid >> 6;                                                 \
    const int g = lane >> 4, r15 = lane & 15;                                                \
    const int m0 = blockIdx.x * 128, n0 = blockIdx.y * 128;                                  \
    const int wm = (w >> 1) * 64, wn = (w & 1) * 64;                                         \
    const f32x4 zero4 = {0.f, 0.f, 0.f, 0.f};                                                \
    f32x4 acc[4][4];                                                                         \
    _Pragma("unroll") for (int i = 0; i < 4; ++i) {                                          \
        _Pragma("unroll") for (int j = 0; j < 4; ++j) acc[i][j] = zero4;                     \
    }                                                                                        \
    const int srow0 = tid >> 3;                                                              \
    const int sj = tid & 7;                                                                  \
    for (int k0 = 0; k0 < Cd; k0 += 64) {                                                    \
        _Pragma("unroll") for (int c = 0; c < 4; ++c) {                                      \
            int row = c * 32 + srow0;                                                        \
            int ch = sj ^ (row & 7);                                                         \
            GLD_LDS16(A + (m0 + row) * Cd + k0 + ch * 8, Alds + (c * 256 + w * 64) * 8);     \
            GLD_LDS16(W + (n0 + row) * Cd + k0 + ch * 8, Blds + (c * 256 + w * 64) * 8);     \
        }                                                                                    \
        __syncthreads();                                                                     \
        _Pragma("unroll") for (int half = 0; half < 2; ++half) {                             \
            f16x8 af[4], bf[4];                                                              \
            _Pragma("unroll") for (int t = 0; t < 4; ++t) {                                  \
                int cidx = ((half << 2) | g) ^ (r15 & 7);                                    \
                af[t] = *(const f16x8*)&Alds[(wm + t * 16 + r15) * 64 + cidx * 8];           \
                bf[t] = *(const f16x8*)&Blds[(wn + t * 16 + r15) * 64 + cidx * 8];           \
            }                                                                                \
            _Pragma("unroll") for (int i = 0; i < 4; ++i) {                                  \
                _Pragma("unroll") for (int j = 0; j < 4; ++j) acc[i][j] =                    \
                    __builtin_amdgcn_mfma_f32_16x16x32_f16(af[i], bf[j], acc[i][j], 0, 0, 0); \
            }                                                                                \
        }                                                                                    \
        __syncthreads();                                                                     \
    }

// ---------------- fused QKV projection GEMM: z=0 Q(+rope), z=1 K(+rope), z=2 V(+transpose) ----
__global__ __launch_bounds__(256, 3) void k_gemm_qkv(
    const f16* __restrict__ qh, const f16* __restrict__ kh, const f16* __restrict__ vh,
    const f16* __restrict__ wqh, const f16* __restrict__ wkh, const f16* __restrict__ wvh,
    f16* __restrict__ Qp, f16* __restrict__ Kp, f16* __restrict__ Vt,
    const float2* __restrict__ csT) {
    __shared__ __attribute__((aligned(16))) char smem[34816];
    f16* Alds = (f16*)smem;
    f16* Blds = (f16*)(smem + 16384);
    const int z = blockIdx.z;
    const f16* A = (z == 0) ? qh : (z == 1) ? kh : vh;
    const f16* W = (z == 0) ? wqh : (z == 1) ? wkh : wvh;
    GEMM_MAINLOOP(A, W)
    if (z < 2) {
        f16* outp = z ? Kp : Qp;
#pragma unroll
        for (int i = 0; i < 4; ++i) {
#pragma unroll
            for (int j = 0; j < 4; ++j) {
#pragma unroll
                for (int r = 0; r < 4; ++r) {
                    int row = m0 + wm + i * 16 + g * 4 + r;
                    int col = n0 + wn + j * 16 + r15;
                    float own = acc[i][j][r];
                    float par = __shfl_xor(own, 1, 64);
                    float2 cs = csT[(row & 2047) * 32 + ((j * 16 + r15) >> 1)];
                    float val = (r15 & 1) ? fmaf(par, cs.y, own * cs.x)
                                          : fmaf(own, cs.x, -par * cs.y);
                    outp[row * Cd + col] = (f16)val;
                }
            }
        }
    } else {
        f16* Clds = (f16*)smem;
#pragma unroll
        for (int i = 0; i < 4; ++i) {
#pragma unroll
            for (int j = 0; j < 4; ++j) {
                f16x4 pv;
#pragma unroll
                for (int r = 0; r < 4; ++r) pv[r] = (f16)acc[i][j][r];
                *(f16x4*)&Clds[(wn + j * 16 + r15) * 136 + wm + i * 16 + g * 4] = pv;
            }
        }
        __syncthreads();
        const int orow = tid >> 1;
        const int th = (tid & 1) * 64;
        const int gcol = n0 + orow;
        const int hh = gcol >> 6, dd = gcol & 63;
        const int bb = m0 >> 11;
        f16* dst = Vt + ((bb * 16 + hh) * 64 + dd) * 2048 + (m0 & 2047) + th;
#pragma unroll
        for (int c = 0; c < 8; ++c) {
            f16x8 vv = *(const f16x8*)&Clds[orow * 136 + th + c * 8];
            *(f16x8*)&dst[c * 8] = vv;
        }
    }
}

// ---------------- output GEMM (f32 out), 128x64 tile -> 512 blocks = 2/CU ----------------
__global__ __launch_bounds__(256, 4) void k_gemm_out(const f16* __restrict__ yh,
                                                     const f16* __restrict__ woh,
                                                     float* __restrict__ out) {
    __shared__ __attribute__((aligned(16))) f16 Alds[128 * 64];
    __shared__ __attribute__((aligned(16))) f16 Blds[64 * 64];
    const int tid = threadIdx.x;
    const int lane = tid & 63, w = tid >> 6;
    const int g = lane >> 4, r15 = lane & 15;
    const int m0 = blockIdx.x * 128, n0 = blockIdx.y * 64;
    const int wm = (w >> 1) * 64, wn = (w & 1) * 32;
    const f32x4 zero4 = {0.f, 0.f, 0.f, 0.f};
    f32x4 acc[4][2];
#pragma unroll
    for (int i = 0; i < 4; ++i) {
#pragma unroll
        for (int j = 0; j < 2; ++j) acc[i][j] = zero4;
    }
    const int srow0 = tid >> 3;
    const int sj = tid & 7;
    for (int k0 = 0; k0 < Cd; k0 += 64) {
#pragma unroll
        for (int c = 0; c < 4; ++c) {
            int row = c * 32 + srow0;
            int ch = sj ^ (row & 7);
            GLD_LDS16(yh + (m0 + row) * Cd + k0 + ch * 8, (f16*)Alds + (c * 256 + w * 64) * 8);
        }
#pragma unroll
        for (int c = 0; c < 2; ++c) {
            int row = c * 32 + srow0;
            int ch = sj ^ (row & 7);
            GLD_LDS16(woh + (n0 + row) * Cd + k0 + ch * 8, (f16*)Blds + (c * 256 + w * 64) * 8);
        }
        __syncthreads();
#pragma unroll
        for (int half = 0; half < 2; ++half) {
            f16x8 af[4], bf[2];
            int cidx = ((half << 2) | g) ^ (r15 & 7);
#pragma unroll
            for (int t = 0; t < 4; ++t)
                af[t] = *(const f16x8*)&Alds[(wm + t * 16 + r15) * 64 + cidx * 8];
#pragma unroll
            for (int t = 0; t < 2; ++t)
                bf[t] = *(const f16x8*)&Blds[(wn + t * 16 + r15) * 64 + cidx * 8];
#pragma unroll
            for (int i = 0; i < 4; ++i) {
#pragma unroll
                for (int j = 0; j < 2; ++j)
                    acc[i][j] =
                        __builtin_amdgcn_mfma_f32_16x16x32_f16(af[i], bf[j], acc[i][j], 0, 0, 0);
            }
        }
        __syncthreads();
    }
#pragma unroll
    for (int i = 0; i < 4; ++i) {
#pragma unroll
        for (int j = 0; j < 2; ++j) {
#pragma unroll
            for (int r = 0; r < 4; ++r) {
                int row = m0 + wm + i * 16 + g * 4 + r;
                int col = n0 + wn + j * 16 + r15;
                out[row * Cd + col] = acc[i][j][r];
            }
        }
    }
}

// ---------------- Flash attention: 4-wave blocks, 6 blocks/CU (24 waves/CU) ----------------
// grid: x = bh (32), y = q-block (16 x 128 rows); 256 threads = 4 waves x 32 q-rows.
// Each wave processes ALL 32 kv-tiles (no split-KV, no merge epilogue). LDS 24KB:
// K double-buffered (2 x 8KB), V SINGLE-buffered (8KB). Race-safety of single V:
//   vmcnt(0) -> barrier1   : own K[t] landed; all threads' K[t] visible AND all PV[t-1] done
//   stage V[t], K[t+1]     : V overwrite safe (PV[t-1] globally complete); issue order V,K
//   QK + softmax           : ~700cy hides V[t] L2 latency (KV is XCD-L2-resident)
//   vmcnt(2) -> barrier2   : own V[t] landed (vmcnt FIFO leaves exactly K[t+1] in flight)
//   PV on V[t]
// All register-array indices compile-time constant (rule #20).
__global__ __launch_bounds__(256, 6) void k_flash(const f16* __restrict__ Qp,
                                                  const f16* __restrict__ Kp,
                                                  const f16* __restrict__ Vt,
                                                  f16* __restrict__ y) {
    __shared__ __attribute__((aligned(16))) f16 Klds[2 * 4096];  // [buf][64kv][64d] src-swizzled
    __shared__ __attribute__((aligned(16))) f16 Vlds[4096];      // [64d][64kv] src-swizzled
    const int bh = blockIdx.x, b = bh >> 4, h = bh & 15;
    const int tid = threadIdx.x, lane = tid & 63, w = tid >> 6;
    const int r31 = lane & 31, hi = lane >> 5;

    // staging: 256 threads x 2 gld_lds cover one 4096-f16 tile (rows 0-31, then 32-63).
    // global chunk pre-XOR-swizzled; (row+32)&7 == row&7 so one swizzle serves both halves.
    const int srow = tid >> 3, sj = tid & 7;  // srow in [0,32)
    const f16* gK = Kp + (b * 2048 + srow) * 1024 + h * 64 + ((sj ^ (srow & 7)) * 8);
    const f16* gV = Vt + (bh * 64 + srow) * 2048 + ((sj ^ (srow & 7)) * 8);
    f16* lK = (f16*)Klds + w * 512;  // wave-uniform base; lane writes base + lane*16B
    f16* lV = (f16*)Vlds + w * 512;

#define STAGE_K(pb, j)                                               \
    do {                                                             \
        GLD_LDS16(gK + (j) * 65536, lK + (pb) * 4096);               \
        GLD_LDS16(gK + (j) * 65536 + 32768, lK + (pb) * 4096 + 2048); \
    } while (0)
#define STAGE_V(j)                                  \
    do {                                            \
        GLD_LDS16(gV + (j) * 64, lV);               \
        GLD_LDS16(gV + (j) * 64 + 65536, lV + 2048); \
    } while (0)

    // Q fragments (B-operand of mfma(K,Q)); 0.125 = 1/sqrt(64), log2e folds exp->exp2
    const int qrow = b * 2048 + blockIdx.y * 128 + w * 32 + r31;
    f16x8 qf[4];
    {
        const f16* qb = Qp + qrow * 1024 + h * 64 + hi * 8;
        const f16 sc = (f16)(0.125f * 1.44269504088896f);
#pragma unroll
        for (int dc = 0; dc < 4; ++dc) {
            f16x8 v = *(const f16x8*)(qb + dc * 16);
#pragma unroll
            for (int j = 0; j < 8; ++j) v[j] = v[j] * sc;
            qf[dc] = v;
        }
    }

    f32x16 o0, o1;
#pragma unroll
    for (int r = 0; r < 16; ++r) { o0[r] = 0.f; o1[r] = 0.f; }
    float m = -1e30f, l = 0.f;

    STAGE_K(0, 0);

    for (int t = 0; t < 32; ++t) {
        asm volatile("s_waitcnt vmcnt(0)" ::: "memory");  // own K[t] landed (issued ~1 iter ago)
        __builtin_amdgcn_sched_barrier(0);
        __builtin_amdgcn_s_barrier();  // all K[t] visible; all PV[t-1] complete
        STAGE_V(t);                    // single buffer: safe now; issue V BEFORE K (vmcnt FIFO)
        if (t < 31) STAGE_K((t + 1) & 1, t + 1);
        const f16* Kb = (const f16*)Klds + (t & 1) * 4096;

        // S^T[kv 64][q 32] = K_tile . Q^T  (lane: col q=r31; rows (r&3)+8*(r>>2)+4*hi (+32))
        f32x16 s0, s1;
#pragma unroll
        for (int r = 0; r < 16; ++r) { s0[r] = 0.f; s1[r] = 0.f; }
        __builtin_amdgcn_s_setprio(1);
#pragma unroll
        for (int dc = 0; dc < 4; ++dc) {
            int j = (2 * dc + hi) ^ (r31 & 7);
            f16x8 k0 = *(const f16x8*)&Kb[r31 * 64 + j * 8];
            f16x8 k1 = *(const f16x8*)&Kb[(32 + r31) * 64 + j * 8];
            s0 = __builtin_amdgcn_mfma_f32_32x32x16_f16(k0, qf[dc], s0, 0, 0, 0);
            s1 = __builtin_amdgcn_mfma_f32_32x32x16_f16(k1, qf[dc], s1, 0, 0, 0);
        }
        __builtin_amdgcn_s_setprio(0);

        // online softmax (log2 domain), defer-max: skip O-rescale while growth <= 8
        float t16[16];
#pragma unroll
        for (int r = 0; r < 16; ++r) t16[r] = fmaxf(s0[r], s1[r]);
        float p0 = MAX3(t16[0], t16[1], t16[2]);
        float p1 = MAX3(t16[3], t16[4], t16[5]);
        float p2 = MAX3(t16[6], t16[7], t16[8]);
        float p3 = MAX3(t16[9], t16[10], t16[11]);
        float p4 = MAX3(t16[12], t16[13], t16[14]);
        float pmax = fmaxf(MAX3(p0, p1, p2), MAX3(p3, p4, t16[15]));
        {
            float2 pm = xhalf_pair(pmax);
            pmax = fmaxf(pm.x, pm.y);
        }
        if (__any(pmax > m + 8.0f)) {
            float mn = fmaxf(m, pmax);
            float cr = EXP2(m - mn);
            m = mn;
            l *= cr;
#pragma unroll
            for (int r = 0; r < 16; ++r) { o0[r] *= cr; o1[r] *= cr; }
        }
#pragma unroll
        for (int r = 0; r < 16; ++r) s0[r] = EXP2(s0[r] - m);
#pragma unroll
        for (int r = 0; r < 16; ++r) s1[r] = EXP2(s1[r] - m);
        // tree-reduce row sum (depth 5)
        float a16[16];
#pragma unroll
        for (int r = 0; r < 16; ++r) a16[r] = s0[r] + s1[r];
#pragma unroll
        for (int r = 0; r < 8; ++r) a16[r] += a16[r + 8];
#pragma unroll
        for (int r = 0; r < 4; ++r) a16[r] += a16[r + 4];
        float rs = (a16[0] + a16[1]) + (a16[2] + a16[3]);

        // pack P pairs to f16 (pk[i] = rows {2i,2i+1} of this lane's kv set)
        unsigned pk[16];
#pragma unroll
        for (int i = 0; i < 8; ++i) {
            auto ha = __builtin_amdgcn_cvt_pkrtz(s0[2 * i], s0[2 * i + 1]);
            __builtin_memcpy(&pk[i], &ha, 4);
            auto hb = __builtin_amdgcn_cvt_pkrtz(s1[2 * i], s1[2 * i + 1]);
            __builtin_memcpy(&pk[8 + i], &hb, 4);
        }

        if (t < 31) {
            asm volatile("s_waitcnt vmcnt(2)" ::: "memory");  // own V[t] landed; K[t+1] in flight
        } else {
            asm volatile("s_waitcnt vmcnt(0)" ::: "memory");
        }
        __builtin_amdgcn_sched_barrier(0);
        __builtin_amdgcn_s_barrier();  // all V[t] visible

        // O^T[d][q] += V^T[d][kv] P[kv][q]; kv k-slices s=0..3 (16 each).
        __builtin_amdgcn_s_setprio(1);
#pragma unroll
        for (int s = 0; s < 4; ++s) {
            const int base = (s >> 1) * 8 + (s & 1) * 4;
            uint2v r0 = __builtin_amdgcn_permlane32_swap(pk[base + 0], pk[base + 2], false, false);
            uint2v r1 = __builtin_amdgcn_permlane32_swap(pk[base + 1], pk[base + 3], false, false);
            union { unsigned u[4]; f16x8 v; } uv;
            uv.u[0] = r0[0];
            uv.u[1] = r1[0];
            uv.u[2] = r0[1];
            uv.u[3] = r1[1];
            int j = (2 * s + hi) ^ (r31 & 7);
            f16x8 v0 = *(const f16x8*)&Vlds[r31 * 64 + j * 8];
            f16x8 v1 = *(const f16x8*)&Vlds[(32 + r31) * 64 + j * 8];
            o0 = __builtin_amdgcn_mfma_f32_32x32x16_f16(v0, uv.v, o0, 0, 0, 0);
            o1 = __builtin_amdgcn_mfma_f32_32x32x16_f16(v1, uv.v, o1, 0, 0, 0);
        }
        __builtin_amdgcn_s_setprio(0);

        // l update off the critical path; cross-half sum via permlane
        {
            float2 rp = xhalf_pair(rs);
            l += rp.x + rp.y;
        }
    }
#undef STAGE_K
#undef STAGE_V

    // epilogue: lane holds O^T[d=(r&3)+8*(r>>2)+4*hi (+32)][q=r31]; normalize + store
    float inv = 1.0f / l;
    f16* yb = y + qrow * 1024 + h * 64 + hi * 4;
#pragma unroll
    for (int rg = 0; rg < 4; ++rg) {
        f16x4 ov;
#pragma unroll
        for (int i = 0; i < 4; ++i) ov[i] = (f16)(o0[rg * 4 + i] * inv);
        *(f16x4*)&yb[rg * 8] = ov;
#pragma unroll
        for (int i = 0; i < 4; ++i) ov[i] = (f16)(o1[rg * 4 + i] * inv);
        *(f16x4*)&yb[32 + rg * 8] = ov;
    }
}

extern "C" void kernel_launch(void* const* d_in, const int* in_sizes, int n_in, void* d_out,
                              int out_size, void* d_ws, size_t ws_size, hipStream_t stream) {
    const float* q = (const float*)d_in[0];
    const float* k = (const float*)d_in[1];
    const float* v = (const float*)d_in[2];
    const float* fr = (const float*)d_in[3];
    const float* wq = (const float*)d_in[4];
    const float* wk = (const float*)d_in[5];
    const float* wv = (const float*)d_in[6];
    const float* wo = (const float*)d_in[7];
    char* ws = (char*)d_ws;

    float2* csT = (float2*)(ws + 0);
    f16* qh = (f16*)(ws + 524288);
    f16* kh = (f16*)(ws + 8912896);
    f16* vh = (f16*)(ws + 17301504);
    f16* wqh = (f16*)(ws + 25690112);
    f16* wkh = (f16*)(ws + 27787264);
    f16* wvh = (f16*)(ws + 29884416);
    f16* woh = (f16*)(ws + 31981568);
    f16* Qp = (f16*)(ws + 34078720);
    f16* Kp = (f16*)(ws + 42467328);
    f16* Vt = (f16*)(ws + 50855936);
    f16* yh = (f16*)(ws + 8912896);  // aliases kh (dead after k_gemm_qkv)

    k_cvt<<<16640, 256, 0, stream>>>(q, k, v, wq, wk, wv, wo, qh, kh, vh, wqh, wkh, wvh, woh,
                                     fr, csT);
    dim3 gqkv(32, 8, 3);
    k_gemm_qkv<<<gqkv, 256, 0, stream>>>(qh, kh, vh, wqh, wkh, wvh, Qp, Kp, Vt, csT);
    dim3 gf(32, 16);
    k_flash<<<gf, 256, 0, stream>>>(Qp, Kp, Vt, yh);
    dim3 go(32, 16);
    k_gemm_out<<<go, 256, 0, stream>>>(yh, woh, (float*)d_out);
}

// Round 16
// 125.557 us; speedup vs baseline: 1.7848x; 1.7848x over previous
//
#include <hip/hip_runtime.h>
#include <stdint.h>

#define Bd 2
#define Td 2048
#define Cd 1024
#define Hd 16
#define HDd 64
#define BT 4096

typedef _Float16 f16;
typedef __attribute__((ext_vector_type(8))) _Float16 f16x8;
typedef __attribute__((ext_vector_type(4))) _Float16 f16x4;
typedef __attribute__((ext_vector_type(2))) _Float16 f16x2;
typedef __attribute__((ext_vector_type(4))) float f32x4;
typedef __attribute__((ext_vector_type(16))) float f32x16;
typedef __attribute__((ext_vector_type(2))) unsigned uint2v;

#define GLD_LDS16(gptr, lptr)                                                        \
    __builtin_amdgcn_global_load_lds((const __attribute__((address_space(1))) void*)(gptr), \
                                     (__attribute__((address_space(3))) void*)(lptr), 16, 0, 0)

#define MAX3(a, b, c) fmaxf(fmaxf(a, b), c)
// raw v_exp_f32: exp2f() without -ffast-math lowers to a ~6-op denorm-guarded libcall;
// softmax inputs are <= 8 and underflow-to-0 is harmless (row max term is always 2^0).
#define EXP2(x) __builtin_amdgcn_exp2f(x)

// cross-half (lane i <-> lane i^32) value pair via permlane32_swap intrinsic (SSA-safe).
__device__ __forceinline__ float2 xhalf_pair(float v) {
    uint2v r = __builtin_amdgcn_permlane32_swap(__float_as_uint(v), __float_as_uint(v), false, false);
    unsigned lo = r[0], hi = r[1];
    float2 out;
    out.x = __uint_as_float(lo);
    out.y = __uint_as_float(hi);
    return out;
}

// ---------------- f32 -> f16 conversion (q,k,v,Wq,Wk,Wv,Wo) + fused trig table ----------------
__global__ void k_cvt(const float* __restrict__ q, const float* __restrict__ k,
                      const float* __restrict__ v, const float* __restrict__ wq,
                      const float* __restrict__ wk, const float* __restrict__ wv,
                      const float* __restrict__ wo, f16* __restrict__ qh, f16* __restrict__ kh,
                      f16* __restrict__ vh, f16* __restrict__ wqh, f16* __restrict__ wkh,
                      f16* __restrict__ wvh, f16* __restrict__ woh,
                      const float* __restrict__ freqs, float2* __restrict__ csT) {
    int g = blockIdx.x * 256 + threadIdx.x;
    if (g >= 4194304) {  // trig tail: 65536 elems
        int i = g - 4194304;
        float f = freqs[i];
        float2 cs;
        cs.x = cosf(f);
        cs.y = sinf(f);
        csT[i] = cs;
        return;
    }
    const float* src;
    f16* dst;
    int base;
    if (g < 1048576)      { src = q;  dst = qh;  base = 0; }
    else if (g < 2097152) { src = k;  dst = kh;  base = 1048576; }
    else if (g < 3145728) { src = v;  dst = vh;  base = 2097152; }
    else if (g < 3407872) { src = wq; dst = wqh; base = 3145728; }
    else if (g < 3670016) { src = wk; dst = wkh; base = 3407872; }
    else if (g < 3932160) { src = wv; dst = wvh; base = 3670016; }
    else                  { src = wo; dst = woh; base = 3932160; }
    int i = g - base;
    float4 val = reinterpret_cast<const float4*>(src)[i];
    f16x4 o;
    o[0] = (f16)val.x; o[1] = (f16)val.y; o[2] = (f16)val.z; o[3] = (f16)val.w;
    reinterpret_cast<f16x4*>(dst)[i] = o;
}

// ---------------- shared GEMM main loop (BK=64, both-sides XOR swizzle, 128x128 tile) ----------
#define GEMM_MAINLOOP(A, W)                                                                  \
    const int tid = threadIdx.x;                                                             \
    const int lane = tid & 63, w = tid >> 6;                                                 \
    const int g = lane >> 4, r15 = lane & 15;                                                \
    const int m0 = blockIdx.x * 128, n0 = blockIdx.y * 128;                                  \
    const int wm = (w >> 1) * 64, wn = (w & 1) * 64;                                         \
    const f32x4 zero4 = {0.f, 0.f, 0.f, 0.f};                                                \
    f32x4 acc[4][4];                                                                         \
    _Pragma("unroll") for (int i = 0; i < 4; ++i) {                                          \
        _Pragma("unroll") for (int j = 0; j < 4; ++j) acc[i][j] = zero4;                     \
    }                                                                                        \
    const int srow0 = tid >> 3;                                                              \
    const int sj = tid & 7;                                                                  \
    for (int k0 = 0; k0 < Cd; k0 += 64) {                                                    \
        _Pragma("unroll") for (int c = 0; c < 4; ++c) {                                      \
            int row = c * 32 + srow0;                                                        \
            int ch = sj ^ (row & 7);                                                         \
            GLD_LDS16(A + (m0 + row) * Cd + k0 + ch * 8, Alds + (c * 256 + w * 64) * 8);     \
            GLD_LDS16(W + (n0 + row) * Cd + k0 + ch * 8, Blds + (c * 256 + w * 64) * 8);     \
        }                                                                                    \
        __syncthreads();                                                                     \
        _Pragma("unroll") for (int half = 0; half < 2; ++half) {                             \
            f16x8 af[4], bf[4];                                                              \
            _Pragma("unroll") for (int t = 0; t < 4; ++t) {                                  \
                int cidx = ((half << 2) | g) ^ (r15 & 7);                                    \
                af[t] = *(const f16x8*)&Alds[(wm + t * 16 + r15) * 64 + cidx * 8];           \
                bf[t] = *(const f16x8*)&Blds[(wn + t * 16 + r15) * 64 + cidx * 8];           \
            }                                                                                \
            _Pragma("unroll") for (int i = 0; i < 4; ++i) {                                  \
                _Pragma("unroll") for (int j = 0; j < 4; ++j) acc[i][j] =                    \
                    __builtin_amdgcn_mfma_f32_16x16x32_f16(af[i], bf[j], acc[i][j], 0, 0, 0); \
            }                                                                                \
        }                                                                                    \
        __syncthreads();                                                                     \
    }

// ---------------- fused QKV projection GEMM: z=0 Q(+rope), z=1 K(+rope), z=2 V(+transpose) ----
__global__ __launch_bounds__(256, 3) void k_gemm_qkv(
    const f16* __restrict__ qh, const f16* __restrict__ kh, const f16* __restrict__ vh,
    const f16* __restrict__ wqh, const f16* __restrict__ wkh, const f16* __restrict__ wvh,
    f16* __restrict__ Qp, f16* __restrict__ Kp, f16* __restrict__ Vt,
    const float2* __restrict__ csT) {
    __shared__ __attribute__((aligned(16))) char smem[34816];
    f16* Alds = (f16*)smem;
    f16* Blds = (f16*)(smem + 16384);
    const int z = blockIdx.z;
    const f16* A = (z == 0) ? qh : (z == 1) ? kh : vh;
    const f16* W = (z == 0) ? wqh : (z == 1) ? wkh : wvh;
    GEMM_MAINLOOP(A, W)
    if (z < 2) {
        f16* outp = z ? Kp : Qp;
#pragma unroll
        for (int i = 0; i < 4; ++i) {
#pragma unroll
            for (int j = 0; j < 4; ++j) {
#pragma unroll
                for (int r = 0; r < 4; ++r) {
                    int row = m0 + wm + i * 16 + g * 4 + r;
                    int col = n0 + wn + j * 16 + r15;
                    float own = acc[i][j][r];
                    float par = __shfl_xor(own, 1, 64);
                    float2 cs = csT[(row & 2047) * 32 + ((j * 16 + r15) >> 1)];
                    float val = (r15 & 1) ? fmaf(par, cs.y, own * cs.x)
                                          : fmaf(own, cs.x, -par * cs.y);
                    outp[row * Cd + col] = (f16)val;
                }
            }
        }
    } else {
        f16* Clds = (f16*)smem;
#pragma unroll
        for (int i = 0; i < 4; ++i) {
#pragma unroll
            for (int j = 0; j < 4; ++j) {
                f16x4 pv;
#pragma unroll
                for (int r = 0; r < 4; ++r) pv[r] = (f16)acc[i][j][r];
                *(f16x4*)&Clds[(wn + j * 16 + r15) * 136 + wm + i * 16 + g * 4] = pv;
            }
        }
        __syncthreads();
        const int orow = tid >> 1;
        const int th = (tid & 1) * 64;
        const int gcol = n0 + orow;
        const int hh = gcol >> 6, dd = gcol & 63;
        const int bb = m0 >> 11;
        f16* dst = Vt + ((bb * 16 + hh) * 64 + dd) * 2048 + (m0 & 2047) + th;
#pragma unroll
        for (int c = 0; c < 8; ++c) {
            f16x8 vv = *(const f16x8*)&Clds[orow * 136 + th + c * 8];
            *(f16x8*)&dst[c * 8] = vv;
        }
    }
}

// ---------------- output GEMM (f32 out), 128x64 tile -> 512 blocks = 2/CU ----------------
__global__ __launch_bounds__(256, 4) void k_gemm_out(const f16* __restrict__ yh,
                                                     const f16* __restrict__ woh,
                                                     float* __restrict__ out) {
    __shared__ __attribute__((aligned(16))) f16 Alds[128 * 64];
    __shared__ __attribute__((aligned(16))) f16 Blds[64 * 64];
    const int tid = threadIdx.x;
    const int lane = tid & 63, w = tid >> 6;
    const int g = lane >> 4, r15 = lane & 15;
    const int m0 = blockIdx.x * 128, n0 = blockIdx.y * 64;
    const int wm = (w >> 1) * 64, wn = (w & 1) * 32;
    const f32x4 zero4 = {0.f, 0.f, 0.f, 0.f};
    f32x4 acc[4][2];
#pragma unroll
    for (int i = 0; i < 4; ++i) {
#pragma unroll
        for (int j = 0; j < 2; ++j) acc[i][j] = zero4;
    }
    const int srow0 = tid >> 3;
    const int sj = tid & 7;
    for (int k0 = 0; k0 < Cd; k0 += 64) {
#pragma unroll
        for (int c = 0; c < 4; ++c) {
            int row = c * 32 + srow0;
            int ch = sj ^ (row & 7);
            GLD_LDS16(yh + (m0 + row) * Cd + k0 + ch * 8, (f16*)Alds + (c * 256 + w * 64) * 8);
        }
#pragma unroll
        for (int c = 0; c < 2; ++c) {
            int row = c * 32 + srow0;
            int ch = sj ^ (row & 7);
            GLD_LDS16(woh + (n0 + row) * Cd + k0 + ch * 8, (f16*)Blds + (c * 256 + w * 64) * 8);
        }
        __syncthreads();
#pragma unroll
        for (int half = 0; half < 2; ++half) {
            f16x8 af[4], bf[2];
            int cidx = ((half << 2) | g) ^ (r15 & 7);
#pragma unroll
            for (int t = 0; t < 4; ++t)
                af[t] = *(const f16x8*)&Alds[(wm + t * 16 + r15) * 64 + cidx * 8];
#pragma unroll
            for (int t = 0; t < 2; ++t)
                bf[t] = *(const f16x8*)&Blds[(wn + t * 16 + r15) * 64 + cidx * 8];
#pragma unroll
            for (int i = 0; i < 4; ++i) {
#pragma unroll
                for (int j = 0; j < 2; ++j)
                    acc[i][j] =
                        __builtin_amdgcn_mfma_f32_16x16x32_f16(af[i], bf[j], acc[i][j], 0, 0, 0);
            }
        }
        __syncthreads();
    }
#pragma unroll
    for (int i = 0; i < 4; ++i) {
#pragma unroll
        for (int j = 0; j < 2; ++j) {
#pragma unroll
            for (int r = 0; r < 4; ++r) {
                int row = m0 + wm + i * 16 + g * 4 + r;
                int col = n0 + wn + j * 16 + r15;
                out[row * Cd + col] = acc[i][j][r];
            }
        }
    }
}

// ---------------- Flash attention: 4-wave blocks, 4 blocks/CU (16 waves/CU) ----------------
// grid: x = bh (32), y = q-block (16 x 128 rows); 256 threads = 4 waves x 32 q-rows.
// Each wave processes ALL 32 kv-tiles (no split-KV, no merge epilogue). LDS 24KB:
// K double-buffered (2 x 8KB), V SINGLE-buffered (8KB). Race-safety of single V:
//   vmcnt(0) -> barrier1   : own K[t] landed; all threads' K[t] visible AND all PV[t-1] done
//   stage V[t], K[t+1]     : V overwrite safe (PV[t-1] globally complete); issue order V,K
//   QK + softmax           : hides V[t] L2 latency (KV is XCD-L2-resident)
//   vmcnt(2) -> barrier2   : own V[t] landed (vmcnt FIFO leaves exactly K[t+1] in flight)
//   PV on V[t]
// launch_bounds(256,4): 128-VGPR budget fits the ~124 live regs. R15's (256,6) capped at
// 85 VGPR -> catastrophic spill (WRITE_SIZE 313MB, 2.7x regression). 6 waves/SIMD is
// arithmetically impossible for this register footprint.
__global__ __launch_bounds__(256, 4) void k_flash(const f16* __restrict__ Qp,
                                                  const f16* __restrict__ Kp,
                                                  const f16* __restrict__ Vt,
                                                  f16* __restrict__ y) {
    __shared__ __attribute__((aligned(16))) f16 Klds[2 * 4096];  // [buf][64kv][64d] src-swizzled
    __shared__ __attribute__((aligned(16))) f16 Vlds[4096];      // [64d][64kv] src-swizzled
    const int bh = blockIdx.x, b = bh >> 4, h = bh & 15;
    const int tid = threadIdx.x, lane = tid & 63, w = tid >> 6;
    const int r31 = lane & 31, hi = lane >> 5;

    // staging: 256 threads x 2 gld_lds cover one 4096-f16 tile (rows 0-31, then 32-63).
    // global chunk pre-XOR-swizzled; (row+32)&7 == row&7 so one swizzle serves both halves.
    const int srow = tid >> 3, sj = tid & 7;  // srow in [0,32)
    const f16* gK = Kp + (b * 2048 + srow) * 1024 + h * 64 + ((sj ^ (srow & 7)) * 8);
    const f16* gV = Vt + (bh * 64 + srow) * 2048 + ((sj ^ (srow & 7)) * 8);
    f16* lK = (f16*)Klds + w * 512;  // wave-uniform base; lane writes base + lane*16B
    f16* lV = (f16*)Vlds + w * 512;

#define STAGE_K(pb, j)                                               \
    do {                                                             \
        GLD_LDS16(gK + (j) * 65536, lK + (pb) * 4096);               \
        GLD_LDS16(gK + (j) * 65536 + 32768, lK + (pb) * 4096 + 2048); \
    } while (0)
#define STAGE_V(j)                                  \
    do {                                            \
        GLD_LDS16(gV + (j) * 64, lV);               \
        GLD_LDS16(gV + (j) * 64 + 65536, lV + 2048); \
    } while (0)

    // Q fragments (B-operand of mfma(K,Q)); 0.125 = 1/sqrt(64), log2e folds exp->exp2
    const int qrow = b * 2048 + blockIdx.y * 128 + w * 32 + r31;
    f16x8 qf[4];
    {
        const f16* qb = Qp + qrow * 1024 + h * 64 + hi * 8;
        const f16 sc = (f16)(0.125f * 1.44269504088896f);
#pragma unroll
        for (int dc = 0; dc < 4; ++dc) {
            f16x8 v = *(const f16x8*)(qb + dc * 16);
#pragma unroll
            for (int j = 0; j < 8; ++j) v[j] = v[j] * sc;
            qf[dc] = v;
        }
    }

    f32x16 o0, o1;
#pragma unroll
    for (int r = 0; r < 16; ++r) { o0[r] = 0.f; o1[r] = 0.f; }
    float m = -1e30f, l = 0.f;

    STAGE_K(0, 0);

    for (int t = 0; t < 32; ++t) {
        asm volatile("s_waitcnt vmcnt(0)" ::: "memory");  // own K[t] landed (issued ~1 iter ago)
        __builtin_amdgcn_sched_barrier(0);
        __builtin_amdgcn_s_barrier();  // all K[t] visible; all PV[t-1] complete
        STAGE_V(t);                    // single buffer: safe now; issue V BEFORE K (vmcnt FIFO)
        if (t < 31) STAGE_K((t + 1) & 1, t + 1);
        const f16* Kb = (const f16*)Klds + (t & 1) * 4096;

        // S^T[kv 64][q 32] = K_tile . Q^T  (lane: col q=r31; rows (r&3)+8*(r>>2)+4*hi (+32))
        f32x16 s0, s1;
#pragma unroll
        for (int r = 0; r < 16; ++r) { s0[r] = 0.f; s1[r] = 0.f; }
        __builtin_amdgcn_s_setprio(1);
#pragma unroll
        for (int dc = 0; dc < 4; ++dc) {
            int j = (2 * dc + hi) ^ (r31 & 7);
            f16x8 k0 = *(const f16x8*)&Kb[r31 * 64 + j * 8];
            f16x8 k1 = *(const f16x8*)&Kb[(32 + r31) * 64 + j * 8];
            s0 = __builtin_amdgcn_mfma_f32_32x32x16_f16(k0, qf[dc], s0, 0, 0, 0);
            s1 = __builtin_amdgcn_mfma_f32_32x32x16_f16(k1, qf[dc], s1, 0, 0, 0);
        }
        __builtin_amdgcn_s_setprio(0);

        // online softmax (log2 domain), defer-max: skip O-rescale while growth <= 8
        float t16[16];
#pragma unroll
        for (int r = 0; r < 16; ++r) t16[r] = fmaxf(s0[r], s1[r]);
        float p0 = MAX3(t16[0], t16[1], t16[2]);
        float p1 = MAX3(t16[3], t16[4], t16[5]);
        float p2 = MAX3(t16[6], t16[7], t16[8]);
        float p3 = MAX3(t16[9], t16[10], t16[11]);
        float p4 = MAX3(t16[12], t16[13], t16[14]);
        float pmax = fmaxf(MAX3(p0, p1, p2), MAX3(p3, p4, t16[15]));
        {
            float2 pm = xhalf_pair(pmax);
            pmax = fmaxf(pm.x, pm.y);
        }
        if (__any(pmax > m + 8.0f)) {
            float mn = fmaxf(m, pmax);
            float cr = EXP2(m - mn);
            m = mn;
            l *= cr;
#pragma unroll
            for (int r = 0; r < 16; ++r) { o0[r] *= cr; o1[r] *= cr; }
        }
#pragma unroll
        for (int r = 0; r < 16; ++r) s0[r] = EXP2(s0[r] - m);
#pragma unroll
        for (int r = 0; r < 16; ++r) s1[r] = EXP2(s1[r] - m);
        // tree-reduce row sum (depth 5)
        float a16[16];
#pragma unroll
        for (int r = 0; r < 16; ++r) a16[r] = s0[r] + s1[r];
#pragma unroll
        for (int r = 0; r < 8; ++r) a16[r] += a16[r + 8];
#pragma unroll
        for (int r = 0; r < 4; ++r) a16[r] += a16[r + 4];
        float rs = (a16[0] + a16[1]) + (a16[2] + a16[3]);

        // pack P pairs to f16 (pk[i] = rows {2i,2i+1} of this lane's kv set)
        unsigned pk[16];
#pragma unroll
        for (int i = 0; i < 8; ++i) {
            auto ha = __builtin_amdgcn_cvt_pkrtz(s0[2 * i], s0[2 * i + 1]);
            __builtin_memcpy(&pk[i], &ha, 4);
            auto hb = __builtin_amdgcn_cvt_pkrtz(s1[2 * i], s1[2 * i + 1]);
            __builtin_memcpy(&pk[8 + i], &hb, 4);
        }

        if (t < 31) {
            asm volatile("s_waitcnt vmcnt(2)" ::: "memory");  // own V[t] landed; K[t+1] in flight
        } else {
            asm volatile("s_waitcnt vmcnt(0)" ::: "memory");
        }
        __builtin_amdgcn_sched_barrier(0);
        __builtin_amdgcn_s_barrier();  // all V[t] visible

        // O^T[d][q] += V^T[d][kv] P[kv][q]; kv k-slices s=0..3 (16 each).
        __builtin_amdgcn_s_setprio(1);
#pragma unroll
        for (int s = 0; s < 4; ++s) {
            const int base = (s >> 1) * 8 + (s & 1) * 4;
            uint2v r0 = __builtin_amdgcn_permlane32_swap(pk[base + 0], pk[base + 2], false, false);
            uint2v r1 = __builtin_amdgcn_permlane32_swap(pk[base + 1], pk[base + 3], false, false);
            union { unsigned u[4]; f16x8 v; } uv;
            uv.u[0] = r0[0];
            uv.u[1] = r1[0];
            uv.u[2] = r0[1];
            uv.u[3] = r1[1];
            int j = (2 * s + hi) ^ (r31 & 7);
            f16x8 v0 = *(const f16x8*)&Vlds[r31 * 64 + j * 8];
            f16x8 v1 = *(const f16x8*)&Vlds[(32 + r31) * 64 + j * 8];
            o0 = __builtin_amdgcn_mfma_f32_32x32x16_f16(v0, uv.v, o0, 0, 0, 0);
            o1 = __builtin_amdgcn_mfma_f32_32x32x16_f16(v1, uv.v, o1, 0, 0, 0);
        }
        __builtin_amdgcn_s_setprio(0);

        // l update off the critical path; cross-half sum via permlane
        {
            float2 rp = xhalf_pair(rs);
            l += rp.x + rp.y;
        }
    }
#undef STAGE_K
#undef STAGE_V

    // epilogue: lane holds O^T[d=(r&3)+8*(r>>2)+4*hi (+32)][q=r31]; normalize + store
    float inv = 1.0f / l;
    f16* yb = y + qrow * 1024 + h * 64 + hi * 4;
#pragma unroll
    for (int rg = 0; rg < 4; ++rg) {
        f16x4 ov;
#pragma unroll
        for (int i = 0; i < 4; ++i) ov[i] = (f16)(o0[rg * 4 + i] * inv);
        *(f16x4*)&yb[rg * 8] = ov;
#pragma unroll
        for (int i = 0; i < 4; ++i) ov[i] = (f16)(o1[rg * 4 + i] * inv);
        *(f16x4*)&yb[32 + rg * 8] = ov;
    }
}

extern "C" void kernel_launch(void* const* d_in, const int* in_sizes, int n_in, void* d_out,
                              int out_size, void* d_ws, size_t ws_size, hipStream_t stream) {
    const float* q = (const float*)d_in[0];
    const float* k = (const float*)d_in[1];
    const float* v = (const float*)d_in[2];
    const float* fr = (const float*)d_in[3];
    const float* wq = (const float*)d_in[4];
    const float* wk = (const float*)d_in[5];
    const float* wv = (const float*)d_in[6];
    const float* wo = (const float*)d_in[7];
    char* ws = (char*)d_ws;

    float2* csT = (float2*)(ws + 0);
    f16* qh = (f16*)(ws + 524288);
    f16* kh = (f16*)(ws + 8912896);
    f16* vh = (f16*)(ws + 17301504);
    f16* wqh = (f16*)(ws + 25690112);
    f16* wkh = (f16*)(ws + 27787264);
    f16* wvh = (f16*)(ws + 29884416);
    f16* woh = (f16*)(ws + 31981568);
    f16* Qp = (f16*)(ws + 34078720);
    f16* Kp = (f16*)(ws + 42467328);
    f16* Vt = (f16*)(ws + 50855936);
    f16* yh = (f16*)(ws + 8912896);  // aliases kh (dead after k_gemm_qkv)

    k_cvt<<<16640, 256, 0, stream>>>(q, k, v, wq, wk, wv, wo, qh, kh, vh, wqh, wkh, wvh, woh,
                                     fr, csT);
    dim3 gqkv(32, 8, 3);
    k_gemm_qkv<<<gqkv, 256, 0, stream>>>(qh, kh, vh, wqh, wkh, wvh, Qp, Kp, Vt, csT);
    dim3 gf(32, 16);
    k_flash<<<gf, 256, 0, stream>>>(Qp, Kp, Vt, yh);
    dim3 go(32, 16);
    k_gemm_out<<<go, 256, 0, stream>>>(yh, woh, (float*)d_out);
}

// Round 17
// 124.021 us; speedup vs baseline: 1.8069x; 1.0124x over previous
//
#include <hip/hip_runtime.h>
#include <stdint.h>

#define Bd 2
#define Td 2048
#define Cd 1024
#define Hd 16
#define HDd 64
#define BT 4096

typedef _Float16 f16;
typedef __attribute__((ext_vector_type(8))) _Float16 f16x8;
typedef __attribute__((ext_vector_type(4))) _Float16 f16x4;
typedef __attribute__((ext_vector_type(2))) _Float16 f16x2;
typedef __attribute__((ext_vector_type(4))) float f32x4;
typedef __attribute__((ext_vector_type(16))) float f32x16;
typedef __attribute__((ext_vector_type(2))) unsigned uint2v;

#define GLD_LDS16(gptr, lptr)                                                        \
    __builtin_amdgcn_global_load_lds((const __attribute__((address_space(1))) void*)(gptr), \
                                     (__attribute__((address_space(3))) void*)(lptr), 16, 0, 0)

#define MAX3(a, b, c) fmaxf(fmaxf(a, b), c)
// raw v_exp_f32: exp2f() without -ffast-math lowers to a ~6-op denorm-guarded libcall;
// softmax inputs are <= 8 and underflow-to-0 is harmless (row max term is always 2^0).
#define EXP2(x) __builtin_amdgcn_exp2f(x)

// cross-half (lane i <-> lane i^32) value pair via permlane32_swap intrinsic (SSA-safe).
__device__ __forceinline__ float2 xhalf_pair(float v) {
    uint2v r = __builtin_amdgcn_permlane32_swap(__float_as_uint(v), __float_as_uint(v), false, false);
    unsigned lo = r[0], hi = r[1];
    float2 out;
    out.x = __uint_as_float(lo);
    out.y = __uint_as_float(hi);
    return out;
}

// ---------------- f32 -> f16 conversion (q,k,v,Wq,Wk,Wv,Wo) + fused trig table ----------------
__global__ void k_cvt(const float* __restrict__ q, const float* __restrict__ k,
                      const float* __restrict__ v, const float* __restrict__ wq,
                      const float* __restrict__ wk, const float* __restrict__ wv,
                      const float* __restrict__ wo, f16* __restrict__ qh, f16* __restrict__ kh,
                      f16* __restrict__ vh, f16* __restrict__ wqh, f16* __restrict__ wkh,
                      f16* __restrict__ wvh, f16* __restrict__ woh,
                      const float* __restrict__ freqs, float2* __restrict__ csT) {
    int g = blockIdx.x * 256 + threadIdx.x;
    if (g >= 4194304) {  // trig tail: 65536 elems
        int i = g - 4194304;
        float f = freqs[i];
        float2 cs;
        cs.x = cosf(f);
        cs.y = sinf(f);
        csT[i] = cs;
        return;
    }
    const float* src;
    f16* dst;
    int base;
    if (g < 1048576)      { src = q;  dst = qh;  base = 0; }
    else if (g < 2097152) { src = k;  dst = kh;  base = 1048576; }
    else if (g < 3145728) { src = v;  dst = vh;  base = 2097152; }
    else if (g < 3407872) { src = wq; dst = wqh; base = 3145728; }
    else if (g < 3670016) { src = wk; dst = wkh; base = 3407872; }
    else if (g < 3932160) { src = wv; dst = wvh; base = 3670016; }
    else                  { src = wo; dst = woh; base = 3932160; }
    int i = g - base;
    float4 val = reinterpret_cast<const float4*>(src)[i];
    f16x4 o;
    o[0] = (f16)val.x; o[1] = (f16)val.y; o[2] = (f16)val.z; o[3] = (f16)val.w;
    reinterpret_cast<f16x4*>(dst)[i] = o;
}

// ---------------- shared GEMM main loop (BK=64, both-sides XOR swizzle, 128x128 tile) ----------
#define GEMM_MAINLOOP(A, W)                                                                  \
    const int tid = threadIdx.x;                                                             \
    const int lane = tid & 63, w = tid >> 6;                                                 \
    const int g = lane >> 4, r15 = lane & 15;                                                \
    const int m0 = blockIdx.x * 128, n0 = blockIdx.y * 128;                                  \
    const int wm = (w >> 1) * 64, wn = (w & 1) * 64;                                         \
    const f32x4 zero4 = {0.f, 0.f, 0.f, 0.f};                                                \
    f32x4 acc[4][4];                                                                         \
    _Pragma("unroll") for (int i = 0; i < 4; ++i) {                                          \
        _Pragma("unroll") for (int j = 0; j < 4; ++j) acc[i][j] = zero4;                     \
    }                                                                                        \
    const int srow0 = tid >> 3;                                                              \
    const int sj = tid & 7;                                                                  \
    for (int k0 = 0; k0 < Cd; k0 += 64) {                                                    \
        _Pragma("unroll") for (int c = 0; c < 4; ++c) {                                      \
            int row = c * 32 + srow0;                                                        \
            int ch = sj ^ (row & 7);                                                         \
            GLD_LDS16(A + (m0 + row) * Cd + k0 + ch * 8, Alds + (c * 256 + w * 64) * 8);     \
            GLD_LDS16(W + (n0 + row) * Cd + k0 + ch * 8, Blds + (c * 256 + w * 64) * 8);     \
        }                                                                                    \
        __syncthreads();                                                                     \
        _Pragma("unroll") for (int half = 0; half < 2; ++half) {                             \
            f16x8 af[4], bf[4];                                                              \
            _Pragma("unroll") for (int t = 0; t < 4; ++t) {                                  \
                int cidx = ((half << 2) | g) ^ (r15 & 7);                                    \
                af[t] = *(const f16x8*)&Alds[(wm + t * 16 + r15) * 64 + cidx * 8];           \
                bf[t] = *(const f16x8*)&Blds[(wn + t * 16 + r15) * 64 + cidx * 8];           \
            }                                                                                \
            _Pragma("unroll") for (int i = 0; i < 4; ++i) {                                  \
                _Pragma("unroll") for (int j = 0; j < 4; ++j) acc[i][j] =                    \
                    __builtin_amdgcn_mfma_f32_16x16x32_f16(af[i], bf[j], acc[i][j], 0, 0, 0); \
            }                                                                                \
        }                                                                                    \
        __syncthreads();                                                                     \
    }

// ---------------- fused QKV projection GEMM: z=0 Q(+rope), z=1 K(+rope), z=2 V(+transpose) ----
__global__ __launch_bounds__(256, 3) void k_gemm_qkv(
    const f16* __restrict__ qh, const f16* __restrict__ kh, const f16* __restrict__ vh,
    const f16* __restrict__ wqh, const f16* __restrict__ wkh, const f16* __restrict__ wvh,
    f16* __restrict__ Qp, f16* __restrict__ Kp, f16* __restrict__ Vt,
    const float2* __restrict__ csT) {
    __shared__ __attribute__((aligned(16))) char smem[34816];
    f16* Alds = (f16*)smem;
    f16* Blds = (f16*)(smem + 16384);
    const int z = blockIdx.z;
    const f16* A = (z == 0) ? qh : (z == 1) ? kh : vh;
    const f16* W = (z == 0) ? wqh : (z == 1) ? wkh : wvh;
    GEMM_MAINLOOP(A, W)
    if (z < 2) {
        f16* outp = z ? Kp : Qp;
#pragma unroll
        for (int i = 0; i < 4; ++i) {
#pragma unroll
            for (int j = 0; j < 4; ++j) {
#pragma unroll
                for (int r = 0; r < 4; ++r) {
                    int row = m0 + wm + i * 16 + g * 4 + r;
                    int col = n0 + wn + j * 16 + r15;
                    float own = acc[i][j][r];
                    float par = __shfl_xor(own, 1, 64);
                    float2 cs = csT[(row & 2047) * 32 + ((j * 16 + r15) >> 1)];
                    float val = (r15 & 1) ? fmaf(par, cs.y, own * cs.x)
                                          : fmaf(own, cs.x, -par * cs.y);
                    outp[row * Cd + col] = (f16)val;
                }
            }
        }
    } else {
        f16* Clds = (f16*)smem;
#pragma unroll
        for (int i = 0; i < 4; ++i) {
#pragma unroll
            for (int j = 0; j < 4; ++j) {
                f16x4 pv;
#pragma unroll
                for (int r = 0; r < 4; ++r) pv[r] = (f16)acc[i][j][r];
                *(f16x4*)&Clds[(wn + j * 16 + r15) * 136 + wm + i * 16 + g * 4] = pv;
            }
        }
        __syncthreads();
        const int orow = tid >> 1;
        const int th = (tid & 1) * 64;
        const int gcol = n0 + orow;
        const int hh = gcol >> 6, dd = gcol & 63;
        const int bb = m0 >> 11;
        f16* dst = Vt + ((bb * 16 + hh) * 64 + dd) * 2048 + (m0 & 2047) + th;
#pragma unroll
        for (int c = 0; c < 8; ++c) {
            f16x8 vv = *(const f16x8*)&Clds[orow * 136 + th + c * 8];
            *(f16x8*)&dst[c * 8] = vv;
        }
    }
}

// ---------------- output GEMM (f32 out), 128x64 tile -> 512 blocks = 2/CU ----------------
__global__ __launch_bounds__(256, 4) void k_gemm_out(const f16* __restrict__ yh,
                                                     const f16* __restrict__ woh,
                                                     float* __restrict__ out) {
    __shared__ __attribute__((aligned(16))) f16 Alds[128 * 64];
    __shared__ __attribute__((aligned(16))) f16 Blds[64 * 64];
    const int tid = threadIdx.x;
    const int lane = tid & 63, w = tid >> 6;
    const int g = lane >> 4, r15 = lane & 15;
    const int m0 = blockIdx.x * 128, n0 = blockIdx.y * 64;
    const int wm = (w >> 1) * 64, wn = (w & 1) * 32;
    const f32x4 zero4 = {0.f, 0.f, 0.f, 0.f};
    f32x4 acc[4][2];
#pragma unroll
    for (int i = 0; i < 4; ++i) {
#pragma unroll
        for (int j = 0; j < 2; ++j) acc[i][j] = zero4;
    }
    const int srow0 = tid >> 3;
    const int sj = tid & 7;
    for (int k0 = 0; k0 < Cd; k0 += 64) {
#pragma unroll
        for (int c = 0; c < 4; ++c) {
            int row = c * 32 + srow0;
            int ch = sj ^ (row & 7);
            GLD_LDS16(yh + (m0 + row) * Cd + k0 + ch * 8, (f16*)Alds + (c * 256 + w * 64) * 8);
        }
#pragma unroll
        for (int c = 0; c < 2; ++c) {
            int row = c * 32 + srow0;
            int ch = sj ^ (row & 7);
            GLD_LDS16(woh + (n0 + row) * Cd + k0 + ch * 8, (f16*)Blds + (c * 256 + w * 64) * 8);
        }
        __syncthreads();
#pragma unroll
        for (int half = 0; half < 2; ++half) {
            f16x8 af[4], bf[2];
            int cidx = ((half << 2) | g) ^ (r15 & 7);
#pragma unroll
            for (int t = 0; t < 4; ++t)
                af[t] = *(const f16x8*)&Alds[(wm + t * 16 + r15) * 64 + cidx * 8];
#pragma unroll
            for (int t = 0; t < 2; ++t)
                bf[t] = *(const f16x8*)&Blds[(wn + t * 16 + r15) * 64 + cidx * 8];
#pragma unroll
            for (int i = 0; i < 4; ++i) {
#pragma unroll
                for (int j = 0; j < 2; ++j)
                    acc[i][j] =
                        __builtin_amdgcn_mfma_f32_16x16x32_f16(af[i], bf[j], acc[i][j], 0, 0, 0);
            }
        }
        __syncthreads();
    }
#pragma unroll
    for (int i = 0; i < 4; ++i) {
#pragma unroll
        for (int j = 0; j < 2; ++j) {
#pragma unroll
            for (int r = 0; r < 4; ++r) {
                int row = m0 + wm + i * 16 + g * 4 + r;
                int col = n0 + wn + j * 16 + r15;
                out[row * Cd + col] = acc[i][j][r];
            }
        }
    }
}

// ---------------- Flash attention: R13 split-KV structure (best measured: 61.3 us) ----------
// grid: x = bh (32), y = q-block (16 x 128 rows) -> 512 blocks = 2/CU = 4 waves/SIMD.
// Waves 0-3 even KV tiles, 4-7 odd; merge partials via LDS at the end.
__global__ __launch_bounds__(512, 4) void k_flash(const f16* __restrict__ Qp,
                                                  const f16* __restrict__ Kp,
                                                  const f16* __restrict__ Vt,
                                                  f16* __restrict__ y) {
    __shared__ __attribute__((aligned(16))) f16 Klds[2 * 2 * 4096];
    __shared__ __attribute__((aligned(16))) f16 Vlds[2 * 2 * 4096];
    const int bh = blockIdx.x, b = bh >> 4, h = bh & 15;
    const int tid = threadIdx.x, lane = tid & 63, w = tid >> 6;
    const int r31 = lane & 31, hi = lane >> 5;
    const int g2 = w >> 2, qw = w & 3;

    const int srow = tid >> 3, sj = tid & 7;
    const f16* gK = Kp + (b * 2048 + srow) * 1024 + h * 64 + ((sj ^ (srow & 7)) * 8);
    const f16* gV = Vt + (bh * 64 + srow) * 2048 + ((sj ^ (srow & 7)) * 8);
    f16* lK = (f16*)Klds + w * 512;
    f16* lV = (f16*)Vlds + w * 512;

#define STAGE_PAIR(pb, pi)                                          \
    do {                                                            \
        GLD_LDS16(gK + (2 * (pi)) * 65536, lK + (pb) * 8192);       \
        GLD_LDS16(gK + (2 * (pi) + 1) * 65536, lK + (pb) * 8192 + 4096); \
        GLD_LDS16(gV + (2 * (pi)) * 64, lV + (pb) * 8192);          \
        GLD_LDS16(gV + (2 * (pi) + 1) * 64, lV + (pb) * 8192 + 4096);   \
    } while (0)

    const int qrow = b * 2048 + blockIdx.y * 128 + qw * 32 + r31;
    f16x8 qf[4];
    {
        const f16* qb = Qp + qrow * 1024 + h * 64 + hi * 8;
        const f16 sc = (f16)(0.125f * 1.44269504088896f);
#pragma unroll
        for (int dc = 0; dc < 4; ++dc) {
            f16x8 v = *(const f16x8*)(qb + dc * 16);
#pragma unroll
            for (int j = 0; j < 8; ++j) v[j] = v[j] * sc;
            qf[dc] = v;
        }
    }

    f32x16 o0, o1;
#pragma unroll
    for (int r = 0; r < 16; ++r) { o0[r] = 0.f; o1[r] = 0.f; }
    float m = -1e30f, l = 0.f;

    STAGE_PAIR(0, 0);

    for (int it = 0; it < 16; ++it) {
        __builtin_amdgcn_s_barrier();
        if (it < 15) {
            STAGE_PAIR((it + 1) & 1, it + 1);
            asm volatile("s_waitcnt vmcnt(4)" ::: "memory");
        } else {
            asm volatile("s_waitcnt vmcnt(0)" ::: "memory");
        }
        __builtin_amdgcn_sched_barrier(0);
        __builtin_amdgcn_s_barrier();
        const f16* Kb = (const f16*)Klds + (it & 1) * 8192 + g2 * 4096;
        const f16* Vb = (const f16*)Vlds + (it & 1) * 8192 + g2 * 4096;

        f32x16 s0, s1;
#pragma unroll
        for (int r = 0; r < 16; ++r) { s0[r] = 0.f; s1[r] = 0.f; }
        __builtin_amdgcn_s_setprio(1);
#pragma unroll
        for (int dc = 0; dc < 4; ++dc) {
            int j = (2 * dc + hi) ^ (r31 & 7);
            f16x8 k0 = *(const f16x8*)&Kb[r31 * 64 + j * 8];
            f16x8 k1 = *(const f16x8*)&Kb[(32 + r31) * 64 + j * 8];
            s0 = __builtin_amdgcn_mfma_f32_32x32x16_f16(k0, qf[dc], s0, 0, 0, 0);
            s1 = __builtin_amdgcn_mfma_f32_32x32x16_f16(k1, qf[dc], s1, 0, 0, 0);
        }
        __builtin_amdgcn_s_setprio(0);

        float t16[16];
#pragma unroll
        for (int r = 0; r < 16; ++r) t16[r] = fmaxf(s0[r], s1[r]);
        float p0 = MAX3(t16[0], t16[1], t16[2]);
        float p1 = MAX3(t16[3], t16[4], t16[5]);
        float p2 = MAX3(t16[6], t16[7], t16[8]);
        float p3 = MAX3(t16[9], t16[10], t16[11]);
        float p4 = MAX3(t16[12], t16[13], t16[14]);
        float pmax = fmaxf(MAX3(p0, p1, p2), MAX3(p3, p4, t16[15]));
        {
            float2 pm = xhalf_pair(pmax);
            pmax = fmaxf(pm.x, pm.y);
        }
        if (__any(pmax > m + 8.0f)) {
            float mn = fmaxf(m, pmax);
            float cr = EXP2(m - mn);
            m = mn;
            l *= cr;
#pragma unroll
            for (int r = 0; r < 16; ++r) { o0[r] *= cr; o1[r] *= cr; }
        }
#pragma unroll
        for (int r = 0; r < 16; ++r) s0[r] = EXP2(s0[r] - m);
#pragma unroll
        for (int r = 0; r < 16; ++r) s1[r] = EXP2(s1[r] - m);
        float a16[16];
#pragma unroll
        for (int r = 0; r < 16; ++r) a16[r] = s0[r] + s1[r];
#pragma unroll
        for (int r = 0; r < 8; ++r) a16[r] += a16[r + 8];
#pragma unroll
        for (int r = 0; r < 4; ++r) a16[r] += a16[r + 4];
        float rs = (a16[0] + a16[1]) + (a16[2] + a16[3]);

        unsigned pk[16];
#pragma unroll
        for (int i = 0; i < 8; ++i) {
            auto ha = __builtin_amdgcn_cvt_pkrtz(s0[2 * i], s0[2 * i + 1]);
            __builtin_memcpy(&pk[i], &ha, 4);
            auto hb = __builtin_amdgcn_cvt_pkrtz(s1[2 * i], s1[2 * i + 1]);
            __builtin_memcpy(&pk[8 + i], &hb, 4);
        }

        __builtin_amdgcn_s_setprio(1);
#pragma unroll
        for (int s = 0; s < 4; ++s) {
            const int base = (s >> 1) * 8 + (s & 1) * 4;
            uint2v r0 = __builtin_amdgcn_permlane32_swap(pk[base + 0], pk[base + 2], false, false);
            uint2v r1 = __builtin_amdgcn_permlane32_swap(pk[base + 1], pk[base + 3], false, false);
            union { unsigned u[4]; f16x8 v; } uv;
            uv.u[0] = r0[0];
            uv.u[1] = r1[0];
            uv.u[2] = r0[1];
            uv.u[3] = r1[1];
            int j = (2 * s + hi) ^ (r31 & 7);
            f16x8 v0 = *(const f16x8*)&Vb[r31 * 64 + j * 8];
            f16x8 v1 = *(const f16x8*)&Vb[(32 + r31) * 64 + j * 8];
            o0 = __builtin_amdgcn_mfma_f32_32x32x16_f16(v0, uv.v, o0, 0, 0, 0);
            o1 = __builtin_amdgcn_mfma_f32_32x32x16_f16(v1, uv.v, o1, 0, 0, 0);
        }
        __builtin_amdgcn_s_setprio(0);

        {
            float2 rp = xhalf_pair(rs);
            l += rp.x + rp.y;
        }
    }
#undef STAGE_PAIR

    __syncthreads();
    float* Ko = (float*)Klds;
    float* Vm = (float*)Vlds;
    if (w >= 4) {
        const int slot = ((w - 4) * 64 + lane) * 32;
#pragma unroll
        for (int c = 0; c < 4; ++c) {
            f32x4 t;
#pragma unroll
            for (int i = 0; i < 4; ++i) t[i] = o0[c * 4 + i];
            *(f32x4*)&Ko[slot + c * 4] = t;
#pragma unroll
            for (int i = 0; i < 4; ++i) t[i] = o1[c * 4 + i];
            *(f32x4*)&Ko[slot + 16 + c * 4] = t;
        }
        Vm[((w - 4) * 64 + lane) * 2] = m;
        Vm[((w - 4) * 64 + lane) * 2 + 1] = l;
    }
    __syncthreads();
    if (w < 4) {
        const int slot = (w * 64 + lane) * 32;
        float mB = Vm[(w * 64 + lane) * 2];
        float lB = Vm[(w * 64 + lane) * 2 + 1];
        float mS = fmaxf(m, mB);
        float sA = EXP2(m - mS), sB = EXP2(mB - mS);
        float linv = 1.0f / (l * sA + lB * sB);
        sA *= linv;
        sB *= linv;
        f16* yb = y + qrow * 1024 + h * 64 + hi * 4;
#pragma unroll
        for (int rg = 0; rg < 4; ++rg) {
            f32x4 pB0 = *(const f32x4*)&Ko[slot + rg * 4];
            f32x4 pB1 = *(const f32x4*)&Ko[slot + 16 + rg * 4];
            f16x4 ov;
#pragma unroll
            for (int i = 0; i < 4; ++i) ov[i] = (f16)(o0[rg * 4 + i] * sA + pB0[i] * sB);
            *(f16x4*)&yb[rg * 8] = ov;
#pragma unroll
            for (int i = 0; i < 4; ++i) ov[i] = (f16)(o1[rg * 4 + i] * sA + pB1[i] * sB);
            *(f16x4*)&yb[32 + rg * 8] = ov;
        }
    }
}

extern "C" void kernel_launch(void* const* d_in, const int* in_sizes, int n_in, void* d_out,
                              int out_size, void* d_ws, size_t ws_size, hipStream_t stream) {
    const float* q = (const float*)d_in[0];
    const float* k = (const float*)d_in[1];
    const float* v = (const float*)d_in[2];
    const float* fr = (const float*)d_in[3];
    const float* wq = (const float*)d_in[4];
    const float* wk = (const float*)d_in[5];
    const float* wv = (const float*)d_in[6];
    const float* wo = (const float*)d_in[7];
    char* ws = (char*)d_ws;

    float2* csT = (float2*)(ws + 0);
    f16* qh = (f16*)(ws + 524288);
    f16* kh = (f16*)(ws + 8912896);
    f16* vh = (f16*)(ws + 17301504);
    f16* wqh = (f16*)(ws + 25690112);
    f16* wkh = (f16*)(ws + 27787264);
    f16* wvh = (f16*)(ws + 29884416);
    f16* woh = (f16*)(ws + 31981568);
    f16* Qp = (f16*)(ws + 34078720);
    f16* Kp = (f16*)(ws + 42467328);
    f16* Vt = (f16*)(ws + 50855936);
    f16* yh = (f16*)(ws + 8912896);  // aliases kh (dead after k_gemm_qkv)

    k_cvt<<<16640, 256, 0, stream>>>(q, k, v, wq, wk, wv, wo, qh, kh, vh, wqh, wkh, wvh, woh,
                                     fr, csT);
    dim3 gqkv(32, 8, 3);
    k_gemm_qkv<<<gqkv, 256, 0, stream>>>(qh, kh, vh, wqh, wkh, wvh, Qp, Kp, Vt, csT);
    dim3 gf(32, 16);
    k_flash<<<gf, 512, 0, stream>>>(Qp, Kp, Vt, yh);
    dim3 go(32, 16);
    k_gemm_out<<<go, 256, 0, stream>>>(yh, woh, (float*)d_out);
}